// Round 6
// baseline (1385.168 us; speedup 1.0000x reference)
//
#include <hip/hip_runtime.h>
#include <math.h>

#define EPSV 1e-5f
#define NSTATB 960

typedef __attribute__((ext_vector_type(8))) short short8;
typedef __attribute__((ext_vector_type(4))) float floatx4;
typedef _Float16 half2v __attribute__((ext_vector_type(2)));

__device__ __forceinline__ float waveSum(float v) {
#pragma unroll
  for (int off = 32; off > 0; off >>= 1) v += __shfl_xor(v, off, 64);
  return v;
}

__device__ __forceinline__ unsigned bfr(float f) {
  union { float f; unsigned u; } v;
  v.f = f;
  return (v.u + 0x7FFFu + ((v.u >> 16) & 1u)) >> 16;  // round-nearest-even
}

// async global->LDS, 16B per lane; lds base wave-uniform (lane scatter is on
// the GLOBAL side only)
__device__ __forceinline__ void gload16(const short* g, short* l) {
  __builtin_amdgcn_global_load_lds(
      (const __attribute__((address_space(1))) void*)g,
      (__attribute__((address_space(3))) void*)l, 16, 0, 0);
}

// ---------------------------------------------------------------------------
// fp32 -> bf16 streaming convert
// ---------------------------------------------------------------------------
__global__ __launch_bounds__(256) void conv_bf16(const float* __restrict__ x,
                                                 short* __restrict__ y, long n4) {
  long i = (long)blockIdx.x * 256 + threadIdx.x;
  long stride = (long)gridDim.x * 256;
  for (; i < n4; i += stride) {
    float4 v = reinterpret_cast<const float4*>(x)[i];
    short4 o;
    o.x = (short)bfr(v.x);
    o.y = (short)bfr(v.y);
    o.z = (short)bfr(v.z);
    o.w = (short)bfr(v.w);
    reinterpret_cast<short4*>(y)[i] = o;
  }
}

// ---------------------------------------------------------------------------
// Transpose + convert: Wt[n*K + k] = bf16(W[k*N + n]); batched over blockIdx.z
// ---------------------------------------------------------------------------
__global__ __launch_bounds__(256) void wT_bf16(const float* __restrict__ W0,
                                               short* __restrict__ Wt0, int K, int N,
                                               long wz) {
  const float* W = W0 + (size_t)blockIdx.z * wz;
  short* Wt = Wt0 + (size_t)blockIdx.z * wz;
  __shared__ short t[32][33];
  int k0 = blockIdx.x * 32, n0 = blockIdx.y * 32;
  int x = threadIdx.x & 31, y = threadIdx.x >> 5;  // 32 x 8
#pragma unroll
  for (int dy = 0; dy < 32; dy += 8) {
    int k = k0 + y + dy, n = n0 + x;
    t[y + dy][x] = (k < K && n < N) ? (short)bfr(W[(size_t)k * N + n]) : (short)0;
  }
  __syncthreads();
#pragma unroll
  for (int dy = 0; dy < 32; dy += 8) {
    int n = n0 + y + dy, k = k0 + x;
    if (n < N && k < K) Wt[(size_t)n * K + k] = t[x][y + dy];
  }
}

// ---------------------------------------------------------------------------
// MFMA GEMM: 256x128 tile, BK=32, 512 thr = 8 waves in 4x2; each wave owns a
// 64x64 sub-tile (acc[4][4]) -> 16 MFMA per 8 ds_read_b128 per K-step per
// wave: HALF the LDS bytes/FLOP of the previous 64x32-wave version (LDS pipe
// was ~47% of kernel time), at UNCHANGED waves/block (R4 lesson).
// 3-slot LDS pipeline, counted vmcnt (stage = 3 gloads -> vmcnt(3)), one raw
// barrier per K-step. LDS LINEAR slots (gload_lds), both-sides chunk swizzle
// c^((row>>1)&3) -> ds_read_b128 at free 2-way conflicts. Output fp32 (Y0) or
// fp16 (Yh0, GAT). nTiles==4 decode keeps the 4 n-tiles of an m-tile on one
// XCD. Fused att-score epilogue (N==512: n-tile == head).
// Requires K%32==0, K>=64, N%128==0. VGPR capped 128 (launch_bounds 512,4)
// -> 2 blocks/CU (LDS 74KB), 16 waves/CU.
// ---------------------------------------------------------------------------
#define ASZ (256 * 32)
#define BSZ (128 * 32)
__global__ __launch_bounds__(512, 4) void gemm_mfma(
    const short* __restrict__ A, const short* __restrict__ Wt0,
    const float* __restrict__ bias, float* __restrict__ Y0,
    _Float16* __restrict__ Yh0, const int* __restrict__ idx0,
    int M, int K, int N, int mTiles, int nTiles,
    long wtZ, long yZ, int idxZ,
    const float* __restrict__ attS0, const float* __restrict__ attD0,
    float* __restrict__ a_s0, float* __restrict__ a_d0, int n_dst) {
  __shared__ short Alds[3 * ASZ];
  __shared__ short Blds[3 * BSZ];
  __shared__ float sred[256][2];
  int z = blockIdx.z;
  int mt, nt;
  if (nTiles == 1) {
    mt = blockIdx.x;
    nt = 0;
  } else {  // nTiles == 4, gridDim.x = Gp*4 with Gp % 8 == 0
    int id = blockIdx.x;
    int slot = id >> 3;
    nt = slot & 3;
    mt = ((slot >> 2) << 3) + (id & 7);
  }
  if (mt >= mTiles) return;
  const short* Wt = Wt0 + (size_t)z * wtZ;
  const int* idx = idx0 ? (idx0 + (size_t)z * idxZ) : nullptr;
  int tid = threadIdx.x;
  int m0 = mt * 256, n0 = nt * 128;

  // staging: A needs 2 rounds of 128 rows; B one round. Thread t covers row
  // (t>>2) (+128 for A round 1), chunk t&3; source chunk swizzled so LDS pos
  // c holds chunk c^((row>>1)&3).
  int srow = tid >> 2, sc = tid & 3;
  int rA0 = srow, rA1 = 128 + srow;
  int swzA0 = sc ^ ((rA0 >> 1) & 3);
  int swzA1 = sc ^ ((rA1 >> 1) & 3);
  int swzB = swzA0;  // same row index as rA0
  int gr0 = m0 + rA0, gr1 = m0 + rA1;
  int ar0 = (gr0 < M) ? (idx ? idx[gr0] : gr0) : 0;  // OOB -> row 0 (discarded)
  int ar1 = (gr1 < M) ? (idx ? idx[gr1] : gr1) : 0;
  const short* aSrc0 = A + (size_t)ar0 * K + swzA0 * 8;
  const short* aSrc1 = A + (size_t)ar1 * K + swzA1 * 8;
  const short* bSrc = Wt + (size_t)(n0 + srow) * K + swzB * 8;
  int wv = tid >> 6, lane = tid & 63;
  int dA0 = wv * 512;         // wave-uniform LDS dests (shorts)
  int dA1 = 4096 + wv * 512;  // rows 128..255
  int dB = wv * 512;

  int wm = (wv & 3) * 64, wn = (wv >> 2) * 64;
  int lr = lane & 15, quad = lane >> 4;
  int aoff[4], boff[4];
#pragma unroll
  for (int i = 0; i < 4; i++) {
    int R = wm + i * 16 + lr;
    aoff[i] = R * 32 + ((quad ^ ((R >> 1) & 3)) << 3);
  }
#pragma unroll
  for (int j = 0; j < 4; j++) {
    int R = wn + j * 16 + lr;
    boff[j] = R * 32 + ((quad ^ ((R >> 1) & 3)) << 3);
  }

  floatx4 acc[4][4];
#pragma unroll
  for (int i = 0; i < 4; i++)
#pragma unroll
    for (int j = 0; j < 4; j++) acc[i][j] = (floatx4)0.f;

  auto stage = [&](int slot, int k) {
    gload16(aSrc0 + k, &Alds[slot * ASZ + dA0]);
    gload16(aSrc1 + k, &Alds[slot * ASZ + dA1]);
    gload16(bSrc + k, &Blds[slot * BSZ + dB]);
  };
  auto compute = [&](int slot) {
    const short* Ab = &Alds[slot * ASZ];
    const short* Bb = &Blds[slot * BSZ];
    short8 af[4], bfv[4];
#pragma unroll
    for (int i = 0; i < 4; i++)
      af[i] = *reinterpret_cast<const short8*>(&Ab[aoff[i]]);
#pragma unroll
    for (int j = 0; j < 4; j++)
      bfv[j] = *reinterpret_cast<const short8*>(&Bb[boff[j]]);
#pragma unroll
    for (int i = 0; i < 4; i++)
#pragma unroll
      for (int j = 0; j < 4; j++)
        acc[i][j] = __builtin_amdgcn_mfma_f32_16x16x32_bf16(af[i], bfv[j],
                                                            acc[i][j], 0, 0, 0);
  };

  // prologue: 2 slots in flight (6 outstanding gloads/wave)
  stage(0, 0);
  stage(1, 32);
  int NT = K >> 5;
  int cur = 0, nxt = 2;
  for (int t = 0; t < NT; ++t) {
    if (t + 1 < NT) {
      asm volatile("s_waitcnt vmcnt(3)" : : : "memory");
    } else {
      asm volatile("s_waitcnt vmcnt(0)" : : : "memory");
    }
    __builtin_amdgcn_s_barrier();
    __builtin_amdgcn_sched_barrier(0);
    if (t + 2 < NT) stage(nxt, 32 * (t + 2));
    compute(cur);
    cur = (cur == 2) ? 0 : cur + 1;
    nxt = (nxt == 2) ? 0 : nxt + 1;
  }

  // epilogue: C/D layout col=lane&15, row=quad*4+reg
#pragma unroll
  for (int i = 0; i < 4; i++) {
#pragma unroll
    for (int j = 0; j < 4; j++) {
      int n = n0 + wn + j * 16 + lr;
      float bv = bias ? bias[n] : 0.f;
#pragma unroll
      for (int r = 0; r < 4; r++) {
        int m = m0 + wm + i * 16 + quad * 4 + r;
        if (m < M) {
          float v = acc[i][j][r] + bv;
          if (Yh0) {
            _Float16* Yh = Yh0 + (size_t)z * yZ;
            Yh[(size_t)m * N + n] = (_Float16)v;
          } else {
            float* Y = Y0 + (size_t)z * yZ;
            Y[(size_t)m * N + n] = v;
          }
        }
      }
    }
  }
  // fused attention scores (GAT path only)
  if (attS0) {
    int h = nt;  // N==512: n-tile == head
    const float* aSb = attS0 + z * 512 + h * 128;
    const float* aDb = attD0 + z * 512 + h * 128;
    float* asv = a_s0 + (size_t)z * M * 4;
    float* adv = a_d0 + (size_t)z * n_dst * 4;
#pragma unroll
    for (int p = 0; p < 2; p++) {
      const float* av = p ? aDb : aSb;
      float w[4];
#pragma unroll
      for (int j = 0; j < 4; j++) w[j] = av[wn + j * 16 + lr];
#pragma unroll
      for (int i = 0; i < 4; i++) {
#pragma unroll
        for (int r = 0; r < 4; r++) {
          float v = acc[i][0][r] * w[0] + acc[i][1][r] * w[1] +
                    acc[i][2][r] * w[2] + acc[i][3][r] * w[3];
          v += __shfl_xor(v, 1, 64);
          v += __shfl_xor(v, 2, 64);
          v += __shfl_xor(v, 4, 64);
          v += __shfl_xor(v, 8, 64);
          if (lr == 0) sred[wm + i * 16 + quad * 4 + r][wv >> 2] = v;
        }
      }
      __syncthreads();
      if (tid < 256) {
        int m = m0 + tid;
        if (m < M) {
          float s = sred[tid][0] + sred[tid][1];
          if (p == 0) asv[(size_t)m * 4 + h] = s;
          else if (m < n_dst) adv[(size_t)m * 4 + h] = s;
        }
      }
      __syncthreads();
    }
  }
}

// ---------------------------------------------------------------------------
// fp32 fallback GEMM (MLP head, N=153)
// ---------------------------------------------------------------------------
__global__ __launch_bounds__(256) void gemm_bias(
    const float* __restrict__ A, const float* __restrict__ W,
    const float* __restrict__ bias, float* __restrict__ Y,
    const int* __restrict__ idx, int M, int K, int N) {
  __shared__ float As[16][65];
  __shared__ float Bs[16][64];
  int tid = threadIdx.x;
  int tx = tid & 15, ty = tid >> 4;
  int m0 = blockIdx.x * 64, n0 = blockIdx.y * 64;
  float acc[4][4] = {};
  for (int k0 = 0; k0 < K; k0 += 16) {
    for (int l = tid; l < 64 * 16; l += 256) {
      int r = l >> 4, kk = l & 15;
      int row = m0 + r;
      float v = 0.f;
      if (row < M) {
        int ar = idx ? idx[row] : row;
        v = A[(size_t)ar * K + k0 + kk];
      }
      As[kk][r] = v;
    }
    for (int l = tid; l < 16 * 64; l += 256) {
      int kk = l >> 6, n = l & 63;
      int col = n0 + n;
      Bs[kk][n] = (col < N) ? W[(size_t)(k0 + kk) * N + col] : 0.f;
    }
    __syncthreads();
#pragma unroll
    for (int kk = 0; kk < 16; kk++) {
      float a[4], b[4];
#pragma unroll
      for (int i = 0; i < 4; i++) a[i] = As[kk][ty + 16 * i];
#pragma unroll
      for (int j = 0; j < 4; j++) b[j] = Bs[kk][tx + 16 * j];
#pragma unroll
      for (int i = 0; i < 4; i++)
#pragma unroll
        for (int j = 0; j < 4; j++) acc[i][j] += a[i] * b[j];
    }
    __syncthreads();
  }
#pragma unroll
  for (int i = 0; i < 4; i++) {
    int m = m0 + ty + 16 * i;
    if (m >= M) continue;
#pragma unroll
    for (int j = 0; j < 4; j++) {
      int n = n0 + tx + 16 * j;
      if (n < N) Y[(size_t)m * N + n] = acc[i][j] + (bias ? bias[n] : 0.f);
    }
  }
}

// ---------------------------------------------------------------------------
// build_starts: depends only on inputs -> hoisted to the head of the stream
// ---------------------------------------------------------------------------
__global__ void build_starts(const int* __restrict__ dst0, int E, int n_dst,
                             int* __restrict__ starts0) {
  const int* dst = dst0 + (size_t)blockIdx.y * E;
  int* starts = starts0 + (size_t)blockIdx.y * (n_dst + 1);
  int k = blockIdx.x * 256 + threadIdx.x;
  if (k > E) return;
  if (k == 0) {
    int d0 = dst[0];
    for (int j = 0; j <= d0; j++) starts[j] = 0;
  } else if (k < E) {
    int d = dst[k], dp = dst[k - 1];
    for (int j = dp + 1; j <= d; j++) starts[j] = k;
  } else {
    int dl = dst[E - 1];
    for (int j = dl + 1; j <= n_dst; j++) starts[j] = E;
  }
}

// ---------------------------------------------------------------------------
// Fused GAT edge softmax + aggregate (replaces edge_logits + node_ms +
// gat_aggregate): 3 passes over the segment's edges recomputing logits from
// a_s/a_d (bitwise-identical numerics; kills the logits/ms buffers and two
// dependent launches). x in fp16; 64 thr, half2/lane covers a 256B head-row.
// ---------------------------------------------------------------------------
__global__ __launch_bounds__(64) void gat_fused(
    const _Float16* __restrict__ x0, const float* __restrict__ a_s0,
    const float* __restrict__ a_d0, const int* __restrict__ src0,
    const int* __restrict__ starts0, const float* __restrict__ bg0,
    float* __restrict__ o0, int n_dst, long xZ, int E, int asZ, int adZ) {
  int z = blockIdx.y;
  const _Float16* x = x0 + (size_t)z * xZ;
  const float* a_s = a_s0 + (size_t)z * asZ;
  const float* a_d = a_d0 + (size_t)z * adZ;
  const int* src = src0 + (size_t)z * E;
  const int* starts = starts0 + (size_t)z * (n_dst + 1);
  const float* bg = bg0 + z * 128;
  float* o = o0 + (size_t)z * (size_t)n_dst * 128;
  int j = blockIdx.x;
  int t = threadIdx.x;  // 0..63, owns channels 2t, 2t+1
  int r0 = starts[j], r1 = starts[j + 1];
  float4 ad = *reinterpret_cast<const float4*>(&a_d[j * 4]);
  // pass 1: per-head max (all threads redundant; uniform loads broadcast)
  float m0 = -1e30f, m1 = -1e30f, m2 = -1e30f, m3 = -1e30f;
  for (int k = r0; k < r1; k++) {
    int s = src[k];
    float4 as = *reinterpret_cast<const float4*>(&a_s[s * 4]);
    float l0 = as.x + ad.x; l0 = (l0 >= 0.f) ? l0 : 0.2f * l0;
    float l1 = as.y + ad.y; l1 = (l1 >= 0.f) ? l1 : 0.2f * l1;
    float l2 = as.z + ad.z; l2 = (l2 >= 0.f) ? l2 : 0.2f * l2;
    float l3 = as.w + ad.w; l3 = (l3 >= 0.f) ? l3 : 0.2f * l3;
    m0 = fmaxf(m0, l0); m1 = fmaxf(m1, l1);
    m2 = fmaxf(m2, l2); m3 = fmaxf(m3, l3);
  }
  // pass 2: per-head sum
  float s0 = 0.f, s1 = 0.f, s2 = 0.f, s3 = 0.f;
  for (int k = r0; k < r1; k++) {
    int s = src[k];
    float4 as = *reinterpret_cast<const float4*>(&a_s[s * 4]);
    float l0 = as.x + ad.x; l0 = (l0 >= 0.f) ? l0 : 0.2f * l0;
    float l1 = as.y + ad.y; l1 = (l1 >= 0.f) ? l1 : 0.2f * l1;
    float l2 = as.z + ad.z; l2 = (l2 >= 0.f) ? l2 : 0.2f * l2;
    float l3 = as.w + ad.w; l3 = (l3 >= 0.f) ? l3 : 0.2f * l3;
    s0 += __expf(l0 - m0); s1 += __expf(l1 - m1);
    s2 += __expf(l2 - m2); s3 += __expf(l3 - m3);
  }
  float i0 = 1.f / fmaxf(s0, 1e-16f);
  float i1 = 1.f / fmaxf(s1, 1e-16f);
  float i2 = 1.f / fmaxf(s2, 1e-16f);
  float i3 = 1.f / fmaxf(s3, 1e-16f);
  // pass 3: weighted accumulate of x rows
  float a00 = 0.f, a01 = 0.f, a10 = 0.f, a11 = 0.f;
  float a20 = 0.f, a21 = 0.f, a30 = 0.f, a31 = 0.f;
  for (int k = r0; k < r1; k++) {
    int s = src[k];
    float4 as = *reinterpret_cast<const float4*>(&a_s[s * 4]);
    float l0 = as.x + ad.x; l0 = (l0 >= 0.f) ? l0 : 0.2f * l0;
    float l1 = as.y + ad.y; l1 = (l1 >= 0.f) ? l1 : 0.2f * l1;
    float l2 = as.z + ad.z; l2 = (l2 >= 0.f) ? l2 : 0.2f * l2;
    float l3 = as.w + ad.w; l3 = (l3 >= 0.f) ? l3 : 0.2f * l3;
    float c0 = __expf(l0 - m0) * i0;
    float c1 = __expf(l1 - m1) * i1;
    float c2 = __expf(l2 - m2) * i2;
    float c3 = __expf(l3 - m3) * i3;
    const half2v* xr = reinterpret_cast<const half2v*>(x + (size_t)s * 512);
    half2v v0 = xr[t];
    half2v v1 = xr[64 + t];
    half2v v2 = xr[128 + t];
    half2v v3 = xr[192 + t];
    a00 += c0 * (float)v0[0]; a01 += c0 * (float)v0[1];
    a10 += c1 * (float)v1[0]; a11 += c1 * (float)v1[1];
    a20 += c2 * (float)v2[0]; a21 += c2 * (float)v2[1];
    a30 += c3 * (float)v3[0]; a31 += c3 * (float)v3[1];
  }
  float2 out;
  out.x = 0.25f * (a00 + a10 + a20 + a30) + bg[2 * t];
  out.y = 0.25f * (a01 + a11 + a21 + a31) + bg[2 * t + 1];
  *reinterpret_cast<float2*>(&o[(size_t)j * 128 + 2 * t]) = out;
}

// ---------------------------------------------------------------------------
// BatchNorm chain — batched over blockIdx.y
// ---------------------------------------------------------------------------
__global__ __launch_bounds__(128) void bn_partial(const float* __restrict__ x0, long xZ,
                                                  float* __restrict__ partial0, int N) {
  const float* x = x0 + (size_t)blockIdx.y * xZ;
  float* partial = partial0 + (size_t)blockIdx.y * (NSTATB * 256);
  int c = threadIdx.x;
  float s = 0.f, ss = 0.f;
  for (int r = blockIdx.x; r < N; r += gridDim.x) {
    float v = x[(size_t)r * 128 + c];
    s += v;
    ss += v * v;
  }
  partial[blockIdx.x * 256 + c] = s;
  partial[blockIdx.x * 256 + 128 + c] = ss;
}

__global__ __launch_bounds__(64) void bn_finalize(const float* __restrict__ partial0,
                                                  int G, int N, float* __restrict__ stats0) {
  const float* partial = partial0 + (size_t)blockIdx.y * (NSTATB * 256);
  float* stats = stats0 + blockIdx.y * 256;
  int c = blockIdx.x;
  int lane = threadIdx.x;
  float s = 0.f, ss = 0.f;
  for (int b = lane; b < G; b += 64) {
    s += partial[b * 256 + c];
    ss += partial[b * 256 + 128 + c];
  }
  s = waveSum(s);
  ss = waveSum(ss);
  if (lane == 0) {
    float mu = s / (float)N;
    float var = ss / (float)N - mu * mu;
    stats[c] = mu;
    stats[128 + c] = rsqrtf(var + EPSV);
  }
}

__global__ __launch_bounds__(128) void bn_apply(
    const float* __restrict__ x0, long xZ, const float* __restrict__ stats0,
    const float* __restrict__ g0, const float* __restrict__ b0, int gz,
    float* __restrict__ y0, short* __restrict__ yb0, long yZ, int M,
    int ostride, int act) {
  int z = blockIdx.y;
  const float* x = x0 + (size_t)z * xZ;
  const float* stats = stats0 + z * 256;
  const float* g = g0 + z * gz;
  const float* b = b0 + z * gz;
  int r = blockIdx.x;
  int c = threadIdx.x;
  if (r >= M) return;
  float v = x[(size_t)r * 128 + c];
  v = (v - stats[c]) * stats[128 + c] * g[c] + b[c];
  if (act == 1) v = (v > 0.f) ? v : (__expf(v) - 1.f);
  if (act == 2) v = fmaxf(v, 0.f);
  if (yb0) {
    short* yb = yb0 + (size_t)z * yZ;
    yb[(size_t)r * ostride + c] = (short)bfr(v);
  } else {
    float* y = y0 + (size_t)z * yZ;
    y[(size_t)r * ostride + c] = v;
  }
}

__global__ __launch_bounds__(128) void pool_attn(
    const float* __restrict__ temp, const float* __restrict__ wp,
    const float* __restrict__ bp, float* __restrict__ sk, int batch) {
  int b = blockIdx.x, c = threadIdx.x;
  int lane = c & 63, wid = c >> 6;
  __shared__ float red[12];
  const float* tr = temp + (size_t)b * 768;
  float wpc = wp[c];
  float t[6];
#pragma unroll
  for (int p = 0; p < 6; p++) t[p] = tr[p * 128 + c];
#pragma unroll
  for (int p = 0; p < 6; p++) {
    float v = waveSum(t[p] * wpc);
    if (lane == 0) red[wid * 6 + p] = v;
  }
  __syncthreads();
  float z[6], m = -1e30f;
#pragma unroll
  for (int p = 0; p < 6; p++) {
    z[p] = red[p] + red[6 + p] + bp[0];
    m = fmaxf(m, z[p]);
  }
  float es = 0.f;
#pragma unroll
  for (int p = 0; p < 6; p++) {
    z[p] = __expf(z[p] - m);
    es += z[p];
  }
  float inv = 1.f / es;
  float o = 0.f;
#pragma unroll
  for (int p = 0; p < 6; p++) o += z[p] * inv * t[p];
  sk[(size_t)b * 128 + c] = o;
}

// ---------------------------------------------------------------------------
extern "C" void kernel_launch(void* const* d_in, const int* in_sizes, int n_in,
                              void* d_out, int out_size, void* d_ws, size_t ws_size,
                              hipStream_t stream) {
  const float* feature = (const float*)d_in[0];
  const int* nodes_idx[2] = {(const int*)d_in[1], (const int*)d_in[4]};
  const int* edge_src[2] = {(const int*)d_in[2], (const int*)d_in[5]};
  const int* edge_dst[2] = {(const int*)d_in[3], (const int*)d_in[6]};
  const float *Wsk[2], *bsk[2], *bng[2], *bnb[2], *Wg[2], *attS[2], *attD[2],
      *bg[2], *wp[2], *bp[2], *pg[2], *pb[2];
  for (int l = 0; l < 2; l++) {
    int base = 7 + l * 12;
    Wsk[l] = (const float*)d_in[base + 0];
    bsk[l] = (const float*)d_in[base + 1];
    bng[l] = (const float*)d_in[base + 2];
    bnb[l] = (const float*)d_in[base + 3];
    Wg[l] = (const float*)d_in[base + 4];
    attS[l] = (const float*)d_in[base + 5];
    attD[l] = (const float*)d_in[base + 6];
    bg[l] = (const float*)d_in[base + 7];
    wp[l] = (const float*)d_in[base + 8];
    bp[l] = (const float*)d_in[base + 9];
    pg[l] = (const float*)d_in[base + 10];
    pb[l] = (const float*)d_in[base + 11];
  }
  const float* Wm1 = (const float*)d_in[31];
  const float* bm1 = (const float*)d_in[32];
  const float* mg = (const float*)d_in[33];
  const float* mb = (const float*)d_in[34];
  const float* Wm2 = (const float*)d_in[35];
  const float* bm2 = (const float*)d_in[36];

  // ---- workspace layout (float units) ----
  float* ws = (float*)d_ws;
  float* bufG5 = ws;   ws += 102400000;  // alias: fp16 x buffer uses half of it
  float* bufSkip = ws; ws += 12800000;   // 100000 * 128
  float* bufO5 = ws;   ws += 19200000;   // 5 * 30000 * 128
  float* temp = ws;    ws += 19200000;   // 25000 * 6 * 128
  float* f1 = ws;      ws += 1024000;    // 8000 * 128
  float* bufH = ws;    ws += 1024000;    // 8000 * 128
  float* a_s5 = ws;    ws += 800000;     // 5 * 40000 * 4
  float* a_d5 = ws;    ws += 600000;     // 5 * 30000 * 4
  float* part = ws;    ws += 5 * NSTATB * 256;
  float* stats = ws;   ws += 5 * 256;
  int* starts5a = (int*)ws; ws += 150080;     // 5 * 30001 ints (L0)
  int* starts5b = (int*)ws; ws += 50080;      // 5 * 10001 ints (L1)
  short* featB = (short*)ws; ws += 25600000;  // 100000*512 bf16
  short* f0b = (short*)ws;   ws += 1600000;   // 25000*128 bf16
  short* wt_sk0 = (short*)ws; ws += 32768;    // 128*512
  short* wt_g0 = (short*)ws;  ws += 655360;   // 5*512*512
  short* wt_sk1 = (short*)ws; ws += 8192;     // 128*128
  short* wt_g1 = (short*)ws;  ws += 163840;   // 5*512*128
  _Float16* bufG5h = (_Float16*)bufG5;        // 5 * 40000 * 512 fp16 (205 MB)

  auto cdiv = [](int a, int b) { return (a + b - 1) / b; };

  // input-only work first (off the critical path)
  build_starts<<<dim3(cdiv(200001, 256), 5), 256, 0, stream>>>(edge_dst[0],
                                                               200000, 30000, starts5a);
  build_starts<<<dim3(cdiv(80001, 256), 5), 256, 0, stream>>>(edge_dst[1],
                                                              80000, 10000, starts5b);
  conv_bf16<<<2048, 256, 0, stream>>>(feature, featB, 100000L * 512 / 4);
  wT_bf16<<<dim3(16, 4, 1), 256, 0, stream>>>(Wsk[0], wt_sk0, 512, 128, 0);
  wT_bf16<<<dim3(16, 16, 5), 256, 0, stream>>>(Wg[0], wt_g0, 512, 512, 512L * 512);
  wT_bf16<<<dim3(4, 4, 1), 256, 0, stream>>>(Wsk[1], wt_sk1, 128, 128, 0);
  wT_bf16<<<dim3(4, 16, 5), 256, 0, stream>>>(Wg[1], wt_g1, 128, 512, 512L * 128);

  auto run_layer = [&](const short* Xb, int Nf, int din, int li, float* fout,
                       short* foutb, const short* wt_sk, const short* wt_g,
                       int* starts5) {
    const int Nsrc = (li == 0) ? 40000 : 20000;
    const int n_dst = (li == 0) ? 30000 : 10000;
    const int batch = (li == 0) ? 25000 : 8000;
    const int E = (li == 0) ? 200000 : 80000;
    const int mtS = cdiv(Nf, 256);
    const int mtG = cdiv(Nsrc, 256);
    const int GpG = cdiv(mtG, 8) * 8;

    // skip branch (fp32 out)
    gemm_mfma<<<dim3(mtS, 1, 1), 512, 0, stream>>>(
        Xb, wt_sk, bsk[li], bufSkip, nullptr, nullptr, Nf, din, 128, mtS, 1,
        0, 0, 0, nullptr, nullptr, nullptr, nullptr, 0);
    bn_partial<<<dim3(NSTATB, 1), 128, 0, stream>>>(bufSkip, 0, part, Nf);
    bn_finalize<<<dim3(128, 1), 64, 0, stream>>>(part, NSTATB, Nf, stats);
    bn_apply<<<dim3(batch, 1), 128, 0, stream>>>(bufSkip, 0, stats, bng[li],
                                                 bnb[li], 0, temp, nullptr, 0,
                                                 batch, 768, 1);

    // all 5 edge types in one launch per stage (fp16 x out + fused scores)
    gemm_mfma<<<dim3(GpG * 4, 1, 5), 512, 0, stream>>>(
        Xb, wt_g, nullptr, nullptr, bufG5h, nodes_idx[li], Nsrc, din, 512,
        mtG, 4, (long)din * 512, (long)Nsrc * 512, Nsrc,
        attS[li], attD[li], a_s5, a_d5, n_dst);
    gat_fused<<<dim3(n_dst, 5), 64, 0, stream>>>(
        bufG5h, a_s5, a_d5, edge_src[li], starts5, bg[li], bufO5, n_dst,
        (long)Nsrc * 512, E, Nsrc * 4, n_dst * 4);
    bn_partial<<<dim3(NSTATB, 5), 128, 0, stream>>>(bufO5, (long)n_dst * 128,
                                                    part, n_dst);
    bn_finalize<<<dim3(128, 5), 64, 0, stream>>>(part, NSTATB, n_dst, stats);
    bn_apply<<<dim3(batch, 5), 128, 0, stream>>>(
        bufO5, (long)n_dst * 128, stats, bng[li] + 128, bnb[li] + 128, 128,
        temp + 128, nullptr, 128, batch, 768, 1);

    // pooling attention + final bn
    pool_attn<<<batch, 128, 0, stream>>>(temp, wp[li], bp[li], bufSkip, batch);
    bn_partial<<<dim3(NSTATB, 1), 128, 0, stream>>>(bufSkip, 0, part, batch);
    bn_finalize<<<dim3(128, 1), 64, 0, stream>>>(part, NSTATB, batch, stats);
    bn_apply<<<dim3(batch, 1), 128, 0, stream>>>(bufSkip, 0, stats, pg[li], pb[li],
                                                 0, fout, foutb, 0, batch, 128, 0);
  };

  run_layer(featB, 100000, 512, 0, nullptr, f0b, wt_sk0, wt_g0, starts5a);
  run_layer(f0b, 25000, 128, 1, f1, nullptr, wt_sk1, wt_g1, starts5b);

  gemm_bias<<<dim3(cdiv(8000, 64), 2), 256, 0, stream>>>(f1, Wm1, bm1, bufSkip,
                                                         nullptr, 8000, 128, 128);
  bn_partial<<<dim3(NSTATB, 1), 128, 0, stream>>>(bufSkip, 0, part, 8000);
  bn_finalize<<<dim3(128, 1), 64, 0, stream>>>(part, NSTATB, 8000, stats);
  bn_apply<<<8000, 128, 0, stream>>>(bufSkip, 0, stats, mg, mb, 0, bufH,
                                     nullptr, 0, 8000, 128, 2);
  gemm_bias<<<dim3(cdiv(8000, 64), 3), 256, 0, stream>>>(
      bufH, Wm2, bm2, (float*)d_out, nullptr, 8000, 128, 153);
}

// Round 7
// 1311.355 us; speedup vs baseline: 1.0563x; 1.0563x over previous
//
#include <hip/hip_runtime.h>
#include <math.h>

#define EPSV 1e-5f
#define NSTATB 960

typedef __attribute__((ext_vector_type(8))) short short8;
typedef __attribute__((ext_vector_type(4))) float floatx4;
typedef _Float16 half2v __attribute__((ext_vector_type(2)));

__device__ __forceinline__ float waveSum(float v) {
#pragma unroll
  for (int off = 32; off > 0; off >>= 1) v += __shfl_xor(v, off, 64);
  return v;
}

__device__ __forceinline__ unsigned bfr(float f) {
  union { float f; unsigned u; } v;
  v.f = f;
  return (v.u + 0x7FFFu + ((v.u >> 16) & 1u)) >> 16;  // round-nearest-even
}

// async global->LDS, 16B per lane; lds base wave-uniform (lane scatter is on
// the GLOBAL side only)
__device__ __forceinline__ void gload16(const short* g, short* l) {
  __builtin_amdgcn_global_load_lds(
      (const __attribute__((address_space(1))) void*)g,
      (__attribute__((address_space(3))) void*)l, 16, 0, 0);
}

// ---------------------------------------------------------------------------
// fp32 -> bf16 streaming convert
// ---------------------------------------------------------------------------
__global__ __launch_bounds__(256) void conv_bf16(const float* __restrict__ x,
                                                 short* __restrict__ y, long n4) {
  long i = (long)blockIdx.x * 256 + threadIdx.x;
  long stride = (long)gridDim.x * 256;
  for (; i < n4; i += stride) {
    float4 v = reinterpret_cast<const float4*>(x)[i];
    short4 o;
    o.x = (short)bfr(v.x);
    o.y = (short)bfr(v.y);
    o.z = (short)bfr(v.z);
    o.w = (short)bfr(v.w);
    reinterpret_cast<short4*>(y)[i] = o;
  }
}

// ---------------------------------------------------------------------------
// Transpose + convert: Wt[n*K + k] = bf16(W[k*N + n]); batched over blockIdx.z
// ---------------------------------------------------------------------------
__global__ __launch_bounds__(256) void wT_bf16(const float* __restrict__ W0,
                                               short* __restrict__ Wt0, int K, int N,
                                               long wz) {
  const float* W = W0 + (size_t)blockIdx.z * wz;
  short* Wt = Wt0 + (size_t)blockIdx.z * wz;
  __shared__ short t[32][33];
  int k0 = blockIdx.x * 32, n0 = blockIdx.y * 32;
  int x = threadIdx.x & 31, y = threadIdx.x >> 5;  // 32 x 8
#pragma unroll
  for (int dy = 0; dy < 32; dy += 8) {
    int k = k0 + y + dy, n = n0 + x;
    t[y + dy][x] = (k < K && n < N) ? (short)bfr(W[(size_t)k * N + n]) : (short)0;
  }
  __syncthreads();
#pragma unroll
  for (int dy = 0; dy < 32; dy += 8) {
    int n = n0 + y + dy, k = k0 + x;
    if (n < N && k < K) Wt[(size_t)n * K + k] = t[x][y + dy];
  }
}

// ---------------------------------------------------------------------------
// MFMA GEMM: 256x128 tile, BK=32, 512 thr = 8 waves in 4x2; each wave owns a
// 64x64 sub-tile (acc[4][4]) -> 16 MFMA per 8 ds_read_b128 per K-step/wave.
// 3-slot LDS pipeline, counted vmcnt (stage = 3 gloads -> vmcnt(3)), one raw
// barrier per K-step. LDS LINEAR slots (gload_lds), both-sides chunk swizzle
// c^((row>>1)&3) -> ds_read_b128 at free 2-way conflicts. Output fp32 (Y0) or
// fp16 (Yh0, GAT). nTiles==4 decode keeps the 4 n-tiles of an m-tile on one
// XCD. Fused att-score epilogue (N==512: n-tile == head).
// Requires K%32==0, K>=64, N%128==0. Proven R6: GAT L0 244.7us.
// ---------------------------------------------------------------------------
#define ASZ (256 * 32)
#define BSZ (128 * 32)
__global__ __launch_bounds__(512, 4) void gemm_mfma(
    const short* __restrict__ A, const short* __restrict__ Wt0,
    const float* __restrict__ bias, float* __restrict__ Y0,
    _Float16* __restrict__ Yh0, const int* __restrict__ idx0,
    int M, int K, int N, int mTiles, int nTiles,
    long wtZ, long yZ, int idxZ,
    const float* __restrict__ attS0, const float* __restrict__ attD0,
    float* __restrict__ a_s0, float* __restrict__ a_d0, int n_dst) {
  __shared__ short Alds[3 * ASZ];
  __shared__ short Blds[3 * BSZ];
  __shared__ float sred[256][2];
  int z = blockIdx.z;
  int mt, nt;
  if (nTiles == 1) {
    mt = blockIdx.x;
    nt = 0;
  } else {  // nTiles == 4, gridDim.x = Gp*4 with Gp % 8 == 0
    int id = blockIdx.x;
    int slot = id >> 3;
    nt = slot & 3;
    mt = ((slot >> 2) << 3) + (id & 7);
  }
  if (mt >= mTiles) return;
  const short* Wt = Wt0 + (size_t)z * wtZ;
  const int* idx = idx0 ? (idx0 + (size_t)z * idxZ) : nullptr;
  int tid = threadIdx.x;
  int m0 = mt * 256, n0 = nt * 128;

  int srow = tid >> 2, sc = tid & 3;
  int rA0 = srow, rA1 = 128 + srow;
  int swzA0 = sc ^ ((rA0 >> 1) & 3);
  int swzA1 = sc ^ ((rA1 >> 1) & 3);
  int swzB = swzA0;  // same row index as rA0
  int gr0 = m0 + rA0, gr1 = m0 + rA1;
  int ar0 = (gr0 < M) ? (idx ? idx[gr0] : gr0) : 0;  // OOB -> row 0 (discarded)
  int ar1 = (gr1 < M) ? (idx ? idx[gr1] : gr1) : 0;
  const short* aSrc0 = A + (size_t)ar0 * K + swzA0 * 8;
  const short* aSrc1 = A + (size_t)ar1 * K + swzA1 * 8;
  const short* bSrc = Wt + (size_t)(n0 + srow) * K + swzB * 8;
  int wv = tid >> 6, lane = tid & 63;
  int dA0 = wv * 512;         // wave-uniform LDS dests (shorts)
  int dA1 = 4096 + wv * 512;  // rows 128..255
  int dB = wv * 512;

  int wm = (wv & 3) * 64, wn = (wv >> 2) * 64;
  int lr = lane & 15, quad = lane >> 4;
  int aoff[4], boff[4];
#pragma unroll
  for (int i = 0; i < 4; i++) {
    int R = wm + i * 16 + lr;
    aoff[i] = R * 32 + ((quad ^ ((R >> 1) & 3)) << 3);
  }
#pragma unroll
  for (int j = 0; j < 4; j++) {
    int R = wn + j * 16 + lr;
    boff[j] = R * 32 + ((quad ^ ((R >> 1) & 3)) << 3);
  }

  floatx4 acc[4][4];
#pragma unroll
  for (int i = 0; i < 4; i++)
#pragma unroll
    for (int j = 0; j < 4; j++) acc[i][j] = (floatx4)0.f;

  auto stage = [&](int slot, int k) {
    gload16(aSrc0 + k, &Alds[slot * ASZ + dA0]);
    gload16(aSrc1 + k, &Alds[slot * ASZ + dA1]);
    gload16(bSrc + k, &Blds[slot * BSZ + dB]);
  };
  auto compute = [&](int slot) {
    const short* Ab = &Alds[slot * ASZ];
    const short* Bb = &Blds[slot * BSZ];
    short8 af[4], bfv[4];
#pragma unroll
    for (int i = 0; i < 4; i++)
      af[i] = *reinterpret_cast<const short8*>(&Ab[aoff[i]]);
#pragma unroll
    for (int j = 0; j < 4; j++)
      bfv[j] = *reinterpret_cast<const short8*>(&Bb[boff[j]]);
#pragma unroll
    for (int i = 0; i < 4; i++)
#pragma unroll
      for (int j = 0; j < 4; j++)
        acc[i][j] = __builtin_amdgcn_mfma_f32_16x16x32_bf16(af[i], bfv[j],
                                                            acc[i][j], 0, 0, 0);
  };

  // prologue: 2 slots in flight (6 outstanding gloads/wave)
  stage(0, 0);
  stage(1, 32);
  int NT = K >> 5;
  int cur = 0, nxt = 2;
  for (int t = 0; t < NT; ++t) {
    if (t + 1 < NT) {
      asm volatile("s_waitcnt vmcnt(3)" : : : "memory");
    } else {
      asm volatile("s_waitcnt vmcnt(0)" : : : "memory");
    }
    __builtin_amdgcn_s_barrier();
    __builtin_amdgcn_sched_barrier(0);
    if (t + 2 < NT) stage(nxt, 32 * (t + 2));
    compute(cur);
    cur = (cur == 2) ? 0 : cur + 1;
    nxt = (nxt == 2) ? 0 : nxt + 1;
  }

  // epilogue: C/D layout col=lane&15, row=quad*4+reg
#pragma unroll
  for (int i = 0; i < 4; i++) {
#pragma unroll
    for (int j = 0; j < 4; j++) {
      int n = n0 + wn + j * 16 + lr;
      float bv = bias ? bias[n] : 0.f;
#pragma unroll
      for (int r = 0; r < 4; r++) {
        int m = m0 + wm + i * 16 + quad * 4 + r;
        if (m < M) {
          float v = acc[i][j][r] + bv;
          if (Yh0) {
            _Float16* Yh = Yh0 + (size_t)z * yZ;
            Yh[(size_t)m * N + n] = (_Float16)v;
          } else {
            float* Y = Y0 + (size_t)z * yZ;
            Y[(size_t)m * N + n] = v;
          }
        }
      }
    }
  }
  // fused attention scores (GAT path only)
  if (attS0) {
    int h = nt;  // N==512: n-tile == head
    const float* aSb = attS0 + z * 512 + h * 128;
    const float* aDb = attD0 + z * 512 + h * 128;
    float* asv = a_s0 + (size_t)z * M * 4;
    float* adv = a_d0 + (size_t)z * n_dst * 4;
#pragma unroll
    for (int p = 0; p < 2; p++) {
      const float* av = p ? aDb : aSb;
      float w[4];
#pragma unroll
      for (int j = 0; j < 4; j++) w[j] = av[wn + j * 16 + lr];
#pragma unroll
      for (int i = 0; i < 4; i++) {
#pragma unroll
        for (int r = 0; r < 4; r++) {
          float v = acc[i][0][r] * w[0] + acc[i][1][r] * w[1] +
                    acc[i][2][r] * w[2] + acc[i][3][r] * w[3];
          v += __shfl_xor(v, 1, 64);
          v += __shfl_xor(v, 2, 64);
          v += __shfl_xor(v, 4, 64);
          v += __shfl_xor(v, 8, 64);
          if (lr == 0) sred[wm + i * 16 + quad * 4 + r][wv >> 2] = v;
        }
      }
      __syncthreads();
      if (tid < 256) {
        int m = m0 + tid;
        if (m < M) {
          float s = sred[tid][0] + sred[tid][1];
          if (p == 0) asv[(size_t)m * 4 + h] = s;
          else if (m < n_dst) adv[(size_t)m * 4 + h] = s;
        }
      }
      __syncthreads();
    }
  }
}

// ---------------------------------------------------------------------------
// fp32 fallback GEMM (MLP head, N=153)
// ---------------------------------------------------------------------------
__global__ __launch_bounds__(256) void gemm_bias(
    const float* __restrict__ A, const float* __restrict__ W,
    const float* __restrict__ bias, float* __restrict__ Y,
    const int* __restrict__ idx, int M, int K, int N) {
  __shared__ float As[16][65];
  __shared__ float Bs[16][64];
  int tid = threadIdx.x;
  int tx = tid & 15, ty = tid >> 4;
  int m0 = blockIdx.x * 64, n0 = blockIdx.y * 64;
  float acc[4][4] = {};
  for (int k0 = 0; k0 < K; k0 += 16) {
    for (int l = tid; l < 64 * 16; l += 256) {
      int r = l >> 4, kk = l & 15;
      int row = m0 + r;
      float v = 0.f;
      if (row < M) {
        int ar = idx ? idx[row] : row;
        v = A[(size_t)ar * K + k0 + kk];
      }
      As[kk][r] = v;
    }
    for (int l = tid; l < 16 * 64; l += 256) {
      int kk = l >> 6, n = l & 63;
      int col = n0 + n;
      Bs[kk][n] = (col < N) ? W[(size_t)(k0 + kk) * N + col] : 0.f;
    }
    __syncthreads();
#pragma unroll
    for (int kk = 0; kk < 16; kk++) {
      float a[4], b[4];
#pragma unroll
      for (int i = 0; i < 4; i++) a[i] = As[kk][ty + 16 * i];
#pragma unroll
      for (int j = 0; j < 4; j++) b[j] = Bs[kk][tx + 16 * j];
#pragma unroll
      for (int i = 0; i < 4; i++)
#pragma unroll
        for (int j = 0; j < 4; j++) acc[i][j] += a[i] * b[j];
    }
    __syncthreads();
  }
#pragma unroll
  for (int i = 0; i < 4; i++) {
    int m = m0 + ty + 16 * i;
    if (m >= M) continue;
#pragma unroll
    for (int j = 0; j < 4; j++) {
      int n = n0 + tx + 16 * j;
      if (n < N) Y[(size_t)m * N + n] = acc[i][j] + (bias ? bias[n] : 0.f);
    }
  }
}

// ---------------------------------------------------------------------------
// build_starts: depends only on inputs -> hoisted to the head of the stream
// ---------------------------------------------------------------------------
__global__ void build_starts(const int* __restrict__ dst0, int E, int n_dst,
                             int* __restrict__ starts0) {
  const int* dst = dst0 + (size_t)blockIdx.y * E;
  int* starts = starts0 + (size_t)blockIdx.y * (n_dst + 1);
  int k = blockIdx.x * 256 + threadIdx.x;
  if (k > E) return;
  if (k == 0) {
    int d0 = dst[0];
    for (int j = 0; j <= d0; j++) starts[j] = 0;
  } else if (k < E) {
    int d = dst[k], dp = dst[k - 1];
    for (int j = dp + 1; j <= d; j++) starts[j] = k;
  } else {
    int dl = dst[E - 1];
    for (int j = dl + 1; j <= n_dst; j++) starts[j] = E;
  }
}

// ---------------------------------------------------------------------------
// Edge/softmax chain (R3-proven): edge_logits (parallel-over-edges, ONE
// coalesced gather pass) -> node_ms (sequential logits re-read) ->
// gat_aggregate (coef inline). Fusing these (R6) regressed -95us: fusion
// multiplied the random-gather passes 3x. Keep them separate.
// ---------------------------------------------------------------------------
__global__ void edge_logits(const int* __restrict__ src0, const int* __restrict__ dst0,
                            const float* __restrict__ a_s0, const float* __restrict__ a_d0,
                            float* __restrict__ logits0, int E, int asZ, int adZ) {
  int z = blockIdx.y;
  const int* src = src0 + (size_t)z * E;
  const int* dst = dst0 + (size_t)z * E;
  const float* a_s = a_s0 + (size_t)z * asZ;
  const float* a_d = a_d0 + (size_t)z * adZ;
  float* logits = logits0 + (size_t)z * E * 4;
  int k = blockIdx.x * 256 + threadIdx.x;
  if (k >= E) return;
  int s = src[k], d = dst[k];
#pragma unroll
  for (int h = 0; h < 4; h++) {
    float v = a_s[s * 4 + h] + a_d[d * 4 + h];
    v = (v >= 0.f) ? v : 0.2f * v;
    logits[k * 4 + h] = v;
  }
}

__global__ void node_ms(const float* __restrict__ logits0, const int* __restrict__ starts0,
                        float* __restrict__ ms0, int n_dst, int E) {
  int z = blockIdx.y;
  const float* logits = logits0 + (size_t)z * E * 4;
  const int* starts = starts0 + (size_t)z * (n_dst + 1);
  float* ms = ms0 + (size_t)z * n_dst * 8;
  int t = blockIdx.x * 256 + threadIdx.x;
  int j = t >> 2, h = t & 3;
  if (j >= n_dst) return;
  int r0 = starts[j], r1 = starts[j + 1];
  float m = -1e30f;
  for (int k = r0; k < r1; k++) m = fmaxf(m, logits[k * 4 + h]);
  float s = 0.f;
  for (int k = r0; k < r1; k++) s += __expf(logits[k * 4 + h] - m);
  ms[j * 8 + h] = m;
  ms[j * 8 + 4 + h] = s;
}

// coef inline from (logits, ms); x in fp16 (64 thr, half2/lane: one wave-load
// covers a full 256B head-row)
__global__ __launch_bounds__(64) void gat_aggregate(
    const _Float16* __restrict__ x0, const float* __restrict__ lg0,
    const int* __restrict__ src0, const int* __restrict__ starts0,
    const float* __restrict__ ms0, const float* __restrict__ bg0,
    float* __restrict__ o0, int n_dst, long xZ, int E) {
  int z = blockIdx.y;
  const _Float16* x = x0 + (size_t)z * xZ;
  const float* lg = lg0 + (size_t)z * E * 4;
  const int* src = src0 + (size_t)z * E;
  const int* starts = starts0 + (size_t)z * (n_dst + 1);
  const float* ms = ms0 + (size_t)z * n_dst * 8;
  const float* bg = bg0 + z * 128;
  float* o = o0 + (size_t)z * (size_t)n_dst * 128;
  int j = blockIdx.x;
  int t = threadIdx.x;  // 0..63, owns channels 2t, 2t+1
  int r0 = starts[j], r1 = starts[j + 1];
  float m0 = ms[j * 8 + 0], m1 = ms[j * 8 + 1];
  float m2 = ms[j * 8 + 2], m3 = ms[j * 8 + 3];
  float i0 = 1.f / fmaxf(ms[j * 8 + 4], 1e-16f);
  float i1 = 1.f / fmaxf(ms[j * 8 + 5], 1e-16f);
  float i2 = 1.f / fmaxf(ms[j * 8 + 6], 1e-16f);
  float i3 = 1.f / fmaxf(ms[j * 8 + 7], 1e-16f);
  float a00 = 0.f, a01 = 0.f, a10 = 0.f, a11 = 0.f;
  float a20 = 0.f, a21 = 0.f, a30 = 0.f, a31 = 0.f;
  for (int k = r0; k < r1; k++) {
    int s = src[k];
    const half2v* xr = reinterpret_cast<const half2v*>(x + (size_t)s * 512);
    half2v v0 = xr[t];
    half2v v1 = xr[64 + t];
    half2v v2 = xr[128 + t];
    half2v v3 = xr[192 + t];
    float c0 = __expf(lg[k * 4 + 0] - m0) * i0;
    float c1 = __expf(lg[k * 4 + 1] - m1) * i1;
    float c2 = __expf(lg[k * 4 + 2] - m2) * i2;
    float c3 = __expf(lg[k * 4 + 3] - m3) * i3;
    a00 += c0 * (float)v0[0];
    a01 += c0 * (float)v0[1];
    a10 += c1 * (float)v1[0];
    a11 += c1 * (float)v1[1];
    a20 += c2 * (float)v2[0];
    a21 += c2 * (float)v2[1];
    a30 += c3 * (float)v3[0];
    a31 += c3 * (float)v3[1];
  }
  float2 out;
  out.x = 0.25f * (a00 + a10 + a20 + a30) + bg[2 * t];
  out.y = 0.25f * (a01 + a11 + a21 + a31) + bg[2 * t + 1];
  *reinterpret_cast<float2*>(&o[(size_t)j * 128 + 2 * t]) = out;
}

// ---------------------------------------------------------------------------
// BatchNorm chain — batched over blockIdx.y
// ---------------------------------------------------------------------------
__global__ __launch_bounds__(128) void bn_partial(const float* __restrict__ x0, long xZ,
                                                  float* __restrict__ partial0, int N) {
  const float* x = x0 + (size_t)blockIdx.y * xZ;
  float* partial = partial0 + (size_t)blockIdx.y * (NSTATB * 256);
  int c = threadIdx.x;
  float s = 0.f, ss = 0.f;
  for (int r = blockIdx.x; r < N; r += gridDim.x) {
    float v = x[(size_t)r * 128 + c];
    s += v;
    ss += v * v;
  }
  partial[blockIdx.x * 256 + c] = s;
  partial[blockIdx.x * 256 + 128 + c] = ss;
}

__global__ __launch_bounds__(64) void bn_finalize(const float* __restrict__ partial0,
                                                  int G, int N, float* __restrict__ stats0) {
  const float* partial = partial0 + (size_t)blockIdx.y * (NSTATB * 256);
  float* stats = stats0 + blockIdx.y * 256;
  int c = blockIdx.x;
  int lane = threadIdx.x;
  float s = 0.f, ss = 0.f;
  for (int b = lane; b < G; b += 64) {
    s += partial[b * 256 + c];
    ss += partial[b * 256 + 128 + c];
  }
  s = waveSum(s);
  ss = waveSum(ss);
  if (lane == 0) {
    float mu = s / (float)N;
    float var = ss / (float)N - mu * mu;
    stats[c] = mu;
    stats[128 + c] = rsqrtf(var + EPSV);
  }
}

__global__ __launch_bounds__(128) void bn_apply(
    const float* __restrict__ x0, long xZ, const float* __restrict__ stats0,
    const float* __restrict__ g0, const float* __restrict__ b0, int gz,
    float* __restrict__ y0, short* __restrict__ yb0, long yZ, int M,
    int ostride, int act) {
  int z = blockIdx.y;
  const float* x = x0 + (size_t)z * xZ;
  const float* stats = stats0 + z * 256;
  const float* g = g0 + z * gz;
  const float* b = b0 + z * gz;
  int r = blockIdx.x;
  int c = threadIdx.x;
  if (r >= M) return;
  float v = x[(size_t)r * 128 + c];
  v = (v - stats[c]) * stats[128 + c] * g[c] + b[c];
  if (act == 1) v = (v > 0.f) ? v : (__expf(v) - 1.f);
  if (act == 2) v = fmaxf(v, 0.f);
  if (yb0) {
    short* yb = yb0 + (size_t)z * yZ;
    yb[(size_t)r * ostride + c] = (short)bfr(v);
  } else {
    float* y = y0 + (size_t)z * yZ;
    y[(size_t)r * ostride + c] = v;
  }
}

__global__ __launch_bounds__(128) void pool_attn(
    const float* __restrict__ temp, const float* __restrict__ wp,
    const float* __restrict__ bp, float* __restrict__ sk, int batch) {
  int b = blockIdx.x, c = threadIdx.x;
  int lane = c & 63, wid = c >> 6;
  __shared__ float red[12];
  const float* tr = temp + (size_t)b * 768;
  float wpc = wp[c];
  float t[6];
#pragma unroll
  for (int p = 0; p < 6; p++) t[p] = tr[p * 128 + c];
#pragma unroll
  for (int p = 0; p < 6; p++) {
    float v = waveSum(t[p] * wpc);
    if (lane == 0) red[wid * 6 + p] = v;
  }
  __syncthreads();
  float z[6], m = -1e30f;
#pragma unroll
  for (int p = 0; p < 6; p++) {
    z[p] = red[p] + red[6 + p] + bp[0];
    m = fmaxf(m, z[p]);
  }
  float es = 0.f;
#pragma unroll
  for (int p = 0; p < 6; p++) {
    z[p] = __expf(z[p] - m);
    es += z[p];
  }
  float inv = 1.f / es;
  float o = 0.f;
#pragma unroll
  for (int p = 0; p < 6; p++) o += z[p] * inv * t[p];
  sk[(size_t)b * 128 + c] = o;
}

// ---------------------------------------------------------------------------
extern "C" void kernel_launch(void* const* d_in, const int* in_sizes, int n_in,
                              void* d_out, int out_size, void* d_ws, size_t ws_size,
                              hipStream_t stream) {
  const float* feature = (const float*)d_in[0];
  const int* nodes_idx[2] = {(const int*)d_in[1], (const int*)d_in[4]};
  const int* edge_src[2] = {(const int*)d_in[2], (const int*)d_in[5]};
  const int* edge_dst[2] = {(const int*)d_in[3], (const int*)d_in[6]};
  const float *Wsk[2], *bsk[2], *bng[2], *bnb[2], *Wg[2], *attS[2], *attD[2],
      *bg[2], *wp[2], *bp[2], *pg[2], *pb[2];
  for (int l = 0; l < 2; l++) {
    int base = 7 + l * 12;
    Wsk[l] = (const float*)d_in[base + 0];
    bsk[l] = (const float*)d_in[base + 1];
    bng[l] = (const float*)d_in[base + 2];
    bnb[l] = (const float*)d_in[base + 3];
    Wg[l] = (const float*)d_in[base + 4];
    attS[l] = (const float*)d_in[base + 5];
    attD[l] = (const float*)d_in[base + 6];
    bg[l] = (const float*)d_in[base + 7];
    wp[l] = (const float*)d_in[base + 8];
    bp[l] = (const float*)d_in[base + 9];
    pg[l] = (const float*)d_in[base + 10];
    pb[l] = (const float*)d_in[base + 11];
  }
  const float* Wm1 = (const float*)d_in[31];
  const float* bm1 = (const float*)d_in[32];
  const float* mg = (const float*)d_in[33];
  const float* mb = (const float*)d_in[34];
  const float* Wm2 = (const float*)d_in[35];
  const float* bm2 = (const float*)d_in[36];

  // ---- workspace layout (float units) ----
  float* ws = (float*)d_ws;
  float* bufG5 = ws;   ws += 102400000;  // alias: fp16 x buffer uses half of it
  float* bufSkip = ws; ws += 12800000;   // 100000 * 128
  float* bufO5 = ws;   ws += 19200000;   // 5 * 30000 * 128
  float* temp = ws;    ws += 19200000;   // 25000 * 6 * 128
  float* f1 = ws;      ws += 1024000;    // 8000 * 128
  float* bufH = ws;    ws += 1024000;    // 8000 * 128
  float* a_s5 = ws;    ws += 800000;     // 5 * 40000 * 4
  float* a_d5 = ws;    ws += 600000;     // 5 * 30000 * 4
  float* logi5 = ws;   ws += 4000000;    // 5 * 200000 * 4
  float* ms5 = ws;     ws += 1200000;    // 5 * 30000 * 8
  float* part = ws;    ws += 5 * NSTATB * 256;
  float* stats = ws;   ws += 5 * 256;
  int* starts5a = (int*)ws; ws += 150080;     // 5 * 30001 ints (L0)
  int* starts5b = (int*)ws; ws += 50080;      // 5 * 10001 ints (L1)
  short* featB = (short*)ws; ws += 25600000;  // 100000*512 bf16
  short* f0b = (short*)ws;   ws += 1600000;   // 25000*128 bf16
  short* wt_sk0 = (short*)ws; ws += 32768;    // 128*512
  short* wt_g0 = (short*)ws;  ws += 655360;   // 5*512*512
  short* wt_sk1 = (short*)ws; ws += 8192;     // 128*128
  short* wt_g1 = (short*)ws;  ws += 163840;   // 5*512*128
  _Float16* bufG5h = (_Float16*)bufG5;        // 5 * 40000 * 512 fp16 (205 MB)

  auto cdiv = [](int a, int b) { return (a + b - 1) / b; };

  // input-only work first (off the critical path)
  build_starts<<<dim3(cdiv(200001, 256), 5), 256, 0, stream>>>(edge_dst[0],
                                                               200000, 30000, starts5a);
  build_starts<<<dim3(cdiv(80001, 256), 5), 256, 0, stream>>>(edge_dst[1],
                                                              80000, 10000, starts5b);
  conv_bf16<<<2048, 256, 0, stream>>>(feature, featB, 100000L * 512 / 4);
  wT_bf16<<<dim3(16, 4, 1), 256, 0, stream>>>(Wsk[0], wt_sk0, 512, 128, 0);
  wT_bf16<<<dim3(16, 16, 5), 256, 0, stream>>>(Wg[0], wt_g0, 512, 512, 512L * 512);
  wT_bf16<<<dim3(4, 4, 1), 256, 0, stream>>>(Wsk[1], wt_sk1, 128, 128, 0);
  wT_bf16<<<dim3(4, 16, 5), 256, 0, stream>>>(Wg[1], wt_g1, 128, 512, 512L * 128);

  auto run_layer = [&](const short* Xb, int Nf, int din, int li, float* fout,
                       short* foutb, const short* wt_sk, const short* wt_g,
                       int* starts5) {
    const int Nsrc = (li == 0) ? 40000 : 20000;
    const int n_dst = (li == 0) ? 30000 : 10000;
    const int batch = (li == 0) ? 25000 : 8000;
    const int E = (li == 0) ? 200000 : 80000;
    const int mtS = cdiv(Nf, 256);
    const int mtG = cdiv(Nsrc, 256);
    const int GpG = cdiv(mtG, 8) * 8;

    // skip branch (fp32 out)
    gemm_mfma<<<dim3(mtS, 1, 1), 512, 0, stream>>>(
        Xb, wt_sk, bsk[li], bufSkip, nullptr, nullptr, Nf, din, 128, mtS, 1,
        0, 0, 0, nullptr, nullptr, nullptr, nullptr, 0);
    bn_partial<<<dim3(NSTATB, 1), 128, 0, stream>>>(bufSkip, 0, part, Nf);
    bn_finalize<<<dim3(128, 1), 64, 0, stream>>>(part, NSTATB, Nf, stats);
    bn_apply<<<dim3(batch, 1), 128, 0, stream>>>(bufSkip, 0, stats, bng[li],
                                                 bnb[li], 0, temp, nullptr, 0,
                                                 batch, 768, 1);

    // all 5 edge types in one launch per stage (fp16 x out + fused scores)
    gemm_mfma<<<dim3(GpG * 4, 1, 5), 512, 0, stream>>>(
        Xb, wt_g, nullptr, nullptr, bufG5h, nodes_idx[li], Nsrc, din, 512,
        mtG, 4, (long)din * 512, (long)Nsrc * 512, Nsrc,
        attS[li], attD[li], a_s5, a_d5, n_dst);
    edge_logits<<<dim3(cdiv(E, 256), 5), 256, 0, stream>>>(
        edge_src[li], edge_dst[li], a_s5, a_d5, logi5, E, Nsrc * 4, n_dst * 4);
    node_ms<<<dim3(cdiv(n_dst * 4, 256), 5), 256, 0, stream>>>(logi5, starts5,
                                                               ms5, n_dst, E);
    gat_aggregate<<<dim3(n_dst, 5), 64, 0, stream>>>(
        bufG5h, logi5, edge_src[li], starts5, ms5, bg[li], bufO5, n_dst,
        (long)Nsrc * 512, E);
    bn_partial<<<dim3(NSTATB, 5), 128, 0, stream>>>(bufO5, (long)n_dst * 128,
                                                    part, n_dst);
    bn_finalize<<<dim3(128, 5), 64, 0, stream>>>(part, NSTATB, n_dst, stats);
    bn_apply<<<dim3(batch, 5), 128, 0, stream>>>(
        bufO5, (long)n_dst * 128, stats, bng[li] + 128, bnb[li] + 128, 128,
        temp + 128, nullptr, 128, batch, 768, 1);

    // pooling attention + final bn
    pool_attn<<<batch, 128, 0, stream>>>(temp, wp[li], bp[li], bufSkip, batch);
    bn_partial<<<dim3(NSTATB, 1), 128, 0, stream>>>(bufSkip, 0, part, batch);
    bn_finalize<<<dim3(128, 1), 64, 0, stream>>>(part, NSTATB, batch, stats);
    bn_apply<<<dim3(batch, 1), 128, 0, stream>>>(bufSkip, 0, stats, pg[li], pb[li],
                                                 0, fout, foutb, 0, batch, 128, 0);
  };

  run_layer(featB, 100000, 512, 0, nullptr, f0b, wt_sk0, wt_g0, starts5a);
  run_layer(f0b, 25000, 128, 1, f1, nullptr, wt_sk1, wt_g1, starts5b);

  gemm_bias<<<dim3(cdiv(8000, 64), 2), 256, 0, stream>>>(f1, Wm1, bm1, bufSkip,
                                                         nullptr, 8000, 128, 128);
  bn_partial<<<dim3(NSTATB, 1), 128, 0, stream>>>(bufSkip, 0, part, 8000);
  bn_finalize<<<dim3(128, 1), 64, 0, stream>>>(part, NSTATB, 8000, stats);
  bn_apply<<<8000, 128, 0, stream>>>(bufSkip, 0, stats, mg, mb, 0, bufH,
                                     nullptr, 0, 8000, 128, 2);
  gemm_bias<<<dim3(cdiv(8000, 64), 3), 256, 0, stream>>>(
      bufH, Wm2, bm2, (float*)d_out, nullptr, 8000, 128, 153);
}

// Round 8
// 1242.929 us; speedup vs baseline: 1.1144x; 1.0551x over previous
//
#include <hip/hip_runtime.h>
#include <math.h>

#define EPSV 1e-5f
#define NSTATB 960

typedef __attribute__((ext_vector_type(8))) short short8;
typedef __attribute__((ext_vector_type(4))) float floatx4;
typedef _Float16 half2v __attribute__((ext_vector_type(2)));

__device__ __forceinline__ float waveSum(float v) {
#pragma unroll
  for (int off = 32; off > 0; off >>= 1) v += __shfl_xor(v, off, 64);
  return v;
}

__device__ __forceinline__ unsigned bfr(float f) {
  union { float f; unsigned u; } v;
  v.f = f;
  return (v.u + 0x7FFFu + ((v.u >> 16) & 1u)) >> 16;  // round-nearest-even
}

// async global->LDS, 16B per lane; lds base wave-uniform (lane scatter is on
// the GLOBAL side only)
__device__ __forceinline__ void gload16(const short* g, short* l) {
  __builtin_amdgcn_global_load_lds(
      (const __attribute__((address_space(1))) void*)g,
      (__attribute__((address_space(3))) void*)l, 16, 0, 0);
}

// ---------------------------------------------------------------------------
// fp32 -> bf16 streaming convert
// ---------------------------------------------------------------------------
__global__ __launch_bounds__(256) void conv_bf16(const float* __restrict__ x,
                                                 short* __restrict__ y, long n4) {
  long i = (long)blockIdx.x * 256 + threadIdx.x;
  long stride = (long)gridDim.x * 256;
  for (; i < n4; i += stride) {
    float4 v = reinterpret_cast<const float4*>(x)[i];
    short4 o;
    o.x = (short)bfr(v.x);
    o.y = (short)bfr(v.y);
    o.z = (short)bfr(v.z);
    o.w = (short)bfr(v.w);
    reinterpret_cast<short4*>(y)[i] = o;
  }
}

// ---------------------------------------------------------------------------
// Transpose + convert: Wt[n*K + k] = bf16(W[k*N + n]); batched over blockIdx.z
// ---------------------------------------------------------------------------
__global__ __launch_bounds__(256) void wT_bf16(const float* __restrict__ W0,
                                               short* __restrict__ Wt0, int K, int N,
                                               long wz) {
  const float* W = W0 + (size_t)blockIdx.z * wz;
  short* Wt = Wt0 + (size_t)blockIdx.z * wz;
  __shared__ short t[32][33];
  int k0 = blockIdx.x * 32, n0 = blockIdx.y * 32;
  int x = threadIdx.x & 31, y = threadIdx.x >> 5;  // 32 x 8
#pragma unroll
  for (int dy = 0; dy < 32; dy += 8) {
    int k = k0 + y + dy, n = n0 + x;
    t[y + dy][x] = (k < K && n < N) ? (short)bfr(W[(size_t)k * N + n]) : (short)0;
  }
  __syncthreads();
#pragma unroll
  for (int dy = 0; dy < 32; dy += 8) {
    int n = n0 + y + dy, k = k0 + x;
    if (n < N && k < K) Wt[(size_t)n * K + k] = t[x][y + dy];
  }
}

// ---------------------------------------------------------------------------
// MFMA GEMM: 256x128 tile, BK=32, 512 thr = 8 waves in 4x2; each wave owns a
// 64x64 sub-tile (acc[4][4]) -> 16 MFMA per 8 ds_read_b128 per K-step/wave.
// 2-slot LDS double-buffer, 50KB LDS -> 3 blocks/CU = 24 waves/CU. Evidence
// R3/R4/R7: MfmaUtil ~ (waves/CU x MFMA-per-phase); 24x16=384 is +50% over
// every previous config; the per-step vmcnt0 drain at __syncthreads is hidden
// by cross-block TLP (m114). LDS LINEAR slots (gload_lds); both-sides chunk
// swizzle c^((row>>1)&3) -> free 2-way ds_read_b128 conflicts. Output fp32
// (Y0) or fp16 (Yh0, GAT). nTiles==4 decode keeps an m-tile's 4 n-tiles on
// one XCD. Fused att-score epilogue (N==512: n-tile == head).
// Requires K%32==0, K>=64, N%128==0.
// ---------------------------------------------------------------------------
#define ASZ (256 * 32)
#define BSZ (128 * 32)
__global__ __launch_bounds__(512, 4) void gemm_mfma(
    const short* __restrict__ A, const short* __restrict__ Wt0,
    const float* __restrict__ bias, float* __restrict__ Y0,
    _Float16* __restrict__ Yh0, const int* __restrict__ idx0,
    int M, int K, int N, int mTiles, int nTiles,
    long wtZ, long yZ, int idxZ,
    const float* __restrict__ attS0, const float* __restrict__ attD0,
    float* __restrict__ a_s0, float* __restrict__ a_d0, int n_dst) {
  __shared__ short Alds[2 * ASZ];
  __shared__ short Blds[2 * BSZ];
  __shared__ float sred[256][2];
  int z = blockIdx.z;
  int mt, nt;
  if (nTiles == 1) {
    mt = blockIdx.x;
    nt = 0;
  } else {  // nTiles == 4, gridDim.x = Gp*4 with Gp % 8 == 0
    int id = blockIdx.x;
    int slot = id >> 3;
    nt = slot & 3;
    mt = ((slot >> 2) << 3) + (id & 7);
  }
  if (mt >= mTiles) return;
  const short* Wt = Wt0 + (size_t)z * wtZ;
  const int* idx = idx0 ? (idx0 + (size_t)z * idxZ) : nullptr;
  int tid = threadIdx.x;
  int m0 = mt * 256, n0 = nt * 128;

  int srow = tid >> 2, sc = tid & 3;
  int rA0 = srow, rA1 = 128 + srow;
  int swzA0 = sc ^ ((rA0 >> 1) & 3);
  int swzA1 = sc ^ ((rA1 >> 1) & 3);
  int swzB = swzA0;  // same row index as rA0
  int gr0 = m0 + rA0, gr1 = m0 + rA1;
  int ar0 = (gr0 < M) ? (idx ? idx[gr0] : gr0) : 0;  // OOB -> row 0 (discarded)
  int ar1 = (gr1 < M) ? (idx ? idx[gr1] : gr1) : 0;
  const short* aSrc0 = A + (size_t)ar0 * K + swzA0 * 8;
  const short* aSrc1 = A + (size_t)ar1 * K + swzA1 * 8;
  const short* bSrc = Wt + (size_t)(n0 + srow) * K + swzB * 8;
  int wv = tid >> 6, lane = tid & 63;
  int dA0 = wv * 512;         // wave-uniform LDS dests (shorts)
  int dA1 = 4096 + wv * 512;  // rows 128..255
  int dB = wv * 512;

  int wm = (wv & 3) * 64, wn = (wv >> 2) * 64;
  int lr = lane & 15, quad = lane >> 4;
  int aoff[4], boff[4];
#pragma unroll
  for (int i = 0; i < 4; i++) {
    int R = wm + i * 16 + lr;
    aoff[i] = R * 32 + ((quad ^ ((R >> 1) & 3)) << 3);
  }
#pragma unroll
  for (int j = 0; j < 4; j++) {
    int R = wn + j * 16 + lr;
    boff[j] = R * 32 + ((quad ^ ((R >> 1) & 3)) << 3);
  }

  floatx4 acc[4][4];
#pragma unroll
  for (int i = 0; i < 4; i++)
#pragma unroll
    for (int j = 0; j < 4; j++) acc[i][j] = (floatx4)0.f;

  auto stage = [&](int slot, int k) {
    gload16(aSrc0 + k, &Alds[slot * ASZ + dA0]);
    gload16(aSrc1 + k, &Alds[slot * ASZ + dA1]);
    gload16(bSrc + k, &Blds[slot * BSZ + dB]);
  };
  auto compute = [&](int slot) {
    const short* Ab = &Alds[slot * ASZ];
    const short* Bb = &Blds[slot * BSZ];
    short8 af[4], bfv[4];
#pragma unroll
    for (int i = 0; i < 4; i++)
      af[i] = *reinterpret_cast<const short8*>(&Ab[aoff[i]]);
#pragma unroll
    for (int j = 0; j < 4; j++)
      bfv[j] = *reinterpret_cast<const short8*>(&Bb[boff[j]]);
#pragma unroll
    for (int i = 0; i < 4; i++)
#pragma unroll
      for (int j = 0; j < 4; j++)
        acc[i][j] = __builtin_amdgcn_mfma_f32_16x16x32_bf16(af[i], bfv[j],
                                                            acc[i][j], 0, 0, 0);
  };

  // 2-slot pipeline: barrier (drains prior stage's loads -> slot cur ready,
  // and all readers of slot nxt are done) -> issue stage(nxt) -> compute(cur).
  stage(0, 0);
  int NT = K >> 5;
  for (int t = 0; t < NT; ++t) {
    __syncthreads();
    if (t + 1 < NT) stage((t + 1) & 1, 32 * (t + 1));
    compute(t & 1);
  }

  // epilogue: C/D layout col=lane&15, row=quad*4+reg
#pragma unroll
  for (int i = 0; i < 4; i++) {
#pragma unroll
    for (int j = 0; j < 4; j++) {
      int n = n0 + wn + j * 16 + lr;
      float bv = bias ? bias[n] : 0.f;
#pragma unroll
      for (int r = 0; r < 4; r++) {
        int m = m0 + wm + i * 16 + quad * 4 + r;
        if (m < M) {
          float v = acc[i][j][r] + bv;
          if (Yh0) {
            _Float16* Yh = Yh0 + (size_t)z * yZ;
            Yh[(size_t)m * N + n] = (_Float16)v;
          } else {
            float* Y = Y0 + (size_t)z * yZ;
            Y[(size_t)m * N + n] = v;
          }
        }
      }
    }
  }
  // fused attention scores (GAT path only)
  if (attS0) {
    int h = nt;  // N==512: n-tile == head
    const float* aSb = attS0 + z * 512 + h * 128;
    const float* aDb = attD0 + z * 512 + h * 128;
    float* asv = a_s0 + (size_t)z * M * 4;
    float* adv = a_d0 + (size_t)z * n_dst * 4;
#pragma unroll
    for (int p = 0; p < 2; p++) {
      const float* av = p ? aDb : aSb;
      float w[4];
#pragma unroll
      for (int j = 0; j < 4; j++) w[j] = av[wn + j * 16 + lr];
#pragma unroll
      for (int i = 0; i < 4; i++) {
#pragma unroll
        for (int r = 0; r < 4; r++) {
          float v = acc[i][0][r] * w[0] + acc[i][1][r] * w[1] +
                    acc[i][2][r] * w[2] + acc[i][3][r] * w[3];
          v += __shfl_xor(v, 1, 64);
          v += __shfl_xor(v, 2, 64);
          v += __shfl_xor(v, 4, 64);
          v += __shfl_xor(v, 8, 64);
          if (lr == 0) sred[wm + i * 16 + quad * 4 + r][wv >> 2] = v;
        }
      }
      __syncthreads();
      if (tid < 256) {
        int m = m0 + tid;
        if (m < M) {
          float s = sred[tid][0] + sred[tid][1];
          if (p == 0) asv[(size_t)m * 4 + h] = s;
          else if (m < n_dst) adv[(size_t)m * 4 + h] = s;
        }
      }
      __syncthreads();
    }
  }
}

// ---------------------------------------------------------------------------
// fp32 fallback GEMM (MLP head, N=153)
// ---------------------------------------------------------------------------
__global__ __launch_bounds__(256) void gemm_bias(
    const float* __restrict__ A, const float* __restrict__ W,
    const float* __restrict__ bias, float* __restrict__ Y,
    const int* __restrict__ idx, int M, int K, int N) {
  __shared__ float As[16][65];
  __shared__ float Bs[16][64];
  int tid = threadIdx.x;
  int tx = tid & 15, ty = tid >> 4;
  int m0 = blockIdx.x * 64, n0 = blockIdx.y * 64;
  float acc[4][4] = {};
  for (int k0 = 0; k0 < K; k0 += 16) {
    for (int l = tid; l < 64 * 16; l += 256) {
      int r = l >> 4, kk = l & 15;
      int row = m0 + r;
      float v = 0.f;
      if (row < M) {
        int ar = idx ? idx[row] : row;
        v = A[(size_t)ar * K + k0 + kk];
      }
      As[kk][r] = v;
    }
    for (int l = tid; l < 16 * 64; l += 256) {
      int kk = l >> 6, n = l & 63;
      int col = n0 + n;
      Bs[kk][n] = (col < N) ? W[(size_t)(k0 + kk) * N + col] : 0.f;
    }
    __syncthreads();
#pragma unroll
    for (int kk = 0; kk < 16; kk++) {
      float a[4], b[4];
#pragma unroll
      for (int i = 0; i < 4; i++) a[i] = As[kk][ty + 16 * i];
#pragma unroll
      for (int j = 0; j < 4; j++) b[j] = Bs[kk][tx + 16 * j];
#pragma unroll
      for (int i = 0; i < 4; i++)
#pragma unroll
        for (int j = 0; j < 4; j++) acc[i][j] += a[i] * b[j];
    }
    __syncthreads();
  }
#pragma unroll
  for (int i = 0; i < 4; i++) {
    int m = m0 + ty + 16 * i;
    if (m >= M) continue;
#pragma unroll
    for (int j = 0; j < 4; j++) {
      int n = n0 + tx + 16 * j;
      if (n < N) Y[(size_t)m * N + n] = acc[i][j] + (bias ? bias[n] : 0.f);
    }
  }
}

// ---------------------------------------------------------------------------
// build_starts: depends only on inputs -> hoisted to the head of the stream
// ---------------------------------------------------------------------------
__global__ void build_starts(const int* __restrict__ dst0, int E, int n_dst,
                             int* __restrict__ starts0) {
  const int* dst = dst0 + (size_t)blockIdx.y * E;
  int* starts = starts0 + (size_t)blockIdx.y * (n_dst + 1);
  int k = blockIdx.x * 256 + threadIdx.x;
  if (k > E) return;
  if (k == 0) {
    int d0 = dst[0];
    for (int j = 0; j <= d0; j++) starts[j] = 0;
  } else if (k < E) {
    int d = dst[k], dp = dst[k - 1];
    for (int j = dp + 1; j <= d; j++) starts[j] = k;
  } else {
    int dl = dst[E - 1];
    for (int j = dl + 1; j <= n_dst; j++) starts[j] = E;
  }
}

// ---------------------------------------------------------------------------
// Edge/softmax chain (R3-proven): edge_logits (ONE coalesced gather pass) ->
// node_ms (sequential logits re-read) -> gat_aggregate (coef inline). R6
// showed fusing these multiplies random-gather passes 3x -> keep separate.
// ---------------------------------------------------------------------------
__global__ void edge_logits(const int* __restrict__ src0, const int* __restrict__ dst0,
                            const float* __restrict__ a_s0, const float* __restrict__ a_d0,
                            float* __restrict__ logits0, int E, int asZ, int adZ) {
  int z = blockIdx.y;
  const int* src = src0 + (size_t)z * E;
  const int* dst = dst0 + (size_t)z * E;
  const float* a_s = a_s0 + (size_t)z * asZ;
  const float* a_d = a_d0 + (size_t)z * adZ;
  float* logits = logits0 + (size_t)z * E * 4;
  int k = blockIdx.x * 256 + threadIdx.x;
  if (k >= E) return;
  int s = src[k], d = dst[k];
#pragma unroll
  for (int h = 0; h < 4; h++) {
    float v = a_s[s * 4 + h] + a_d[d * 4 + h];
    v = (v >= 0.f) ? v : 0.2f * v;
    logits[k * 4 + h] = v;
  }
}

__global__ void node_ms(const float* __restrict__ logits0, const int* __restrict__ starts0,
                        float* __restrict__ ms0, int n_dst, int E) {
  int z = blockIdx.y;
  const float* logits = logits0 + (size_t)z * E * 4;
  const int* starts = starts0 + (size_t)z * (n_dst + 1);
  float* ms = ms0 + (size_t)z * n_dst * 8;
  int t = blockIdx.x * 256 + threadIdx.x;
  int j = t >> 2, h = t & 3;
  if (j >= n_dst) return;
  int r0 = starts[j], r1 = starts[j + 1];
  float m = -1e30f;
  for (int k = r0; k < r1; k++) m = fmaxf(m, logits[k * 4 + h]);
  float s = 0.f;
  for (int k = r0; k < r1; k++) s += __expf(logits[k * 4 + h] - m);
  ms[j * 8 + h] = m;
  ms[j * 8 + 4 + h] = s;
}

// coef inline from (logits, ms); x in fp16 (64 thr, half2/lane: one wave-load
// covers a full 256B head-row)
__global__ __launch_bounds__(64) void gat_aggregate(
    const _Float16* __restrict__ x0, const float* __restrict__ lg0,
    const int* __restrict__ src0, const int* __restrict__ starts0,
    const float* __restrict__ ms0, const float* __restrict__ bg0,
    float* __restrict__ o0, int n_dst, long xZ, int E) {
  int z = blockIdx.y;
  const _Float16* x = x0 + (size_t)z * xZ;
  const float* lg = lg0 + (size_t)z * E * 4;
  const int* src = src0 + (size_t)z * E;
  const int* starts = starts0 + (size_t)z * (n_dst + 1);
  const float* ms = ms0 + (size_t)z * n_dst * 8;
  const float* bg = bg0 + z * 128;
  float* o = o0 + (size_t)z * (size_t)n_dst * 128;
  int j = blockIdx.x;
  int t = threadIdx.x;  // 0..63, owns channels 2t, 2t+1
  int r0 = starts[j], r1 = starts[j + 1];
  float m0 = ms[j * 8 + 0], m1 = ms[j * 8 + 1];
  float m2 = ms[j * 8 + 2], m3 = ms[j * 8 + 3];
  float i0 = 1.f / fmaxf(ms[j * 8 + 4], 1e-16f);
  float i1 = 1.f / fmaxf(ms[j * 8 + 5], 1e-16f);
  float i2 = 1.f / fmaxf(ms[j * 8 + 6], 1e-16f);
  float i3 = 1.f / fmaxf(ms[j * 8 + 7], 1e-16f);
  float a00 = 0.f, a01 = 0.f, a10 = 0.f, a11 = 0.f;
  float a20 = 0.f, a21 = 0.f, a30 = 0.f, a31 = 0.f;
  for (int k = r0; k < r1; k++) {
    int s = src[k];
    const half2v* xr = reinterpret_cast<const half2v*>(x + (size_t)s * 512);
    half2v v0 = xr[t];
    half2v v1 = xr[64 + t];
    half2v v2 = xr[128 + t];
    half2v v3 = xr[192 + t];
    float c0 = __expf(lg[k * 4 + 0] - m0) * i0;
    float c1 = __expf(lg[k * 4 + 1] - m1) * i1;
    float c2 = __expf(lg[k * 4 + 2] - m2) * i2;
    float c3 = __expf(lg[k * 4 + 3] - m3) * i3;
    a00 += c0 * (float)v0[0];
    a01 += c0 * (float)v0[1];
    a10 += c1 * (float)v1[0];
    a11 += c1 * (float)v1[1];
    a20 += c2 * (float)v2[0];
    a21 += c2 * (float)v2[1];
    a30 += c3 * (float)v3[0];
    a31 += c3 * (float)v3[1];
  }
  float2 out;
  out.x = 0.25f * (a00 + a10 + a20 + a30) + bg[2 * t];
  out.y = 0.25f * (a01 + a11 + a21 + a31) + bg[2 * t + 1];
  *reinterpret_cast<float2*>(&o[(size_t)j * 128 + 2 * t]) = out;
}

// ---------------------------------------------------------------------------
// BatchNorm chain — batched over blockIdx.y
// ---------------------------------------------------------------------------
__global__ __launch_bounds__(128) void bn_partial(const float* __restrict__ x0, long xZ,
                                                  float* __restrict__ partial0, int N) {
  const float* x = x0 + (size_t)blockIdx.y * xZ;
  float* partial = partial0 + (size_t)blockIdx.y * (NSTATB * 256);
  int c = threadIdx.x;
  float s = 0.f, ss = 0.f;
  for (int r = blockIdx.x; r < N; r += gridDim.x) {
    float v = x[(size_t)r * 128 + c];
    s += v;
    ss += v * v;
  }
  partial[blockIdx.x * 256 + c] = s;
  partial[blockIdx.x * 256 + 128 + c] = ss;
}

__global__ __launch_bounds__(64) void bn_finalize(const float* __restrict__ partial0,
                                                  int G, int N, float* __restrict__ stats0) {
  const float* partial = partial0 + (size_t)blockIdx.y * (NSTATB * 256);
  float* stats = stats0 + blockIdx.y * 256;
  int c = blockIdx.x;
  int lane = threadIdx.x;
  float s = 0.f, ss = 0.f;
  for (int b = lane; b < G; b += 64) {
    s += partial[b * 256 + c];
    ss += partial[b * 256 + 128 + c];
  }
  s = waveSum(s);
  ss = waveSum(ss);
  if (lane == 0) {
    float mu = s / (float)N;
    float var = ss / (float)N - mu * mu;
    stats[c] = mu;
    stats[128 + c] = rsqrtf(var + EPSV);
  }
}

__global__ __launch_bounds__(128) void bn_apply(
    const float* __restrict__ x0, long xZ, const float* __restrict__ stats0,
    const float* __restrict__ g0, const float* __restrict__ b0, int gz,
    float* __restrict__ y0, short* __restrict__ yb0, long yZ, int M,
    int ostride, int act) {
  int z = blockIdx.y;
  const float* x = x0 + (size_t)z * xZ;
  const float* stats = stats0 + z * 256;
  const float* g = g0 + z * gz;
  const float* b = b0 + z * gz;
  int r = blockIdx.x;
  int c = threadIdx.x;
  if (r >= M) return;
  float v = x[(size_t)r * 128 + c];
  v = (v - stats[c]) * stats[128 + c] * g[c] + b[c];
  if (act == 1) v = (v > 0.f) ? v : (__expf(v) - 1.f);
  if (act == 2) v = fmaxf(v, 0.f);
  if (yb0) {
    short* yb = yb0 + (size_t)z * yZ;
    yb[(size_t)r * ostride + c] = (short)bfr(v);
  } else {
    float* y = y0 + (size_t)z * yZ;
    y[(size_t)r * ostride + c] = v;
  }
}

// ---------------------------------------------------------------------------
// Fused pool: reads RAW skip (bufSkip) + RAW gat outs (bufO5) + bn stats
// (slot 0 = skip, slots 1..5 = gat), applies bn+ELU inline (identical
// arithmetic/order to the old bn_apply->temp->pool_attn path), then pooling
// attention. Kills 2 bn_apply launches + 154MB temp roundtrip per L0 layer.
// ---------------------------------------------------------------------------
__global__ __launch_bounds__(128) void pool_fused(
    const float* __restrict__ skipB, const float* __restrict__ o5, long oZ,
    const float* __restrict__ stats, const float* __restrict__ g6,
    const float* __restrict__ b6, const float* __restrict__ wp,
    const float* __restrict__ bp, float* __restrict__ sk, int batch) {
  int b = blockIdx.x, c = threadIdx.x;
  int lane = c & 63, wid = c >> 6;
  __shared__ float red[12];
  float wpc = wp[c];
  float t[6];
  {
    float v = skipB[(size_t)b * 128 + c];
    v = (v - stats[c]) * stats[128 + c] * g6[c] + b6[c];
    t[0] = (v > 0.f) ? v : (__expf(v) - 1.f);
  }
#pragma unroll
  for (int p = 1; p < 6; p++) {
    const float* st = stats + p * 256;
    float v = o5[(size_t)(p - 1) * oZ + (size_t)b * 128 + c];
    v = (v - st[c]) * st[128 + c] * g6[p * 128 + c] + b6[p * 128 + c];
    t[p] = (v > 0.f) ? v : (__expf(v) - 1.f);
  }
#pragma unroll
  for (int p = 0; p < 6; p++) {
    float v = waveSum(t[p] * wpc);
    if (lane == 0) red[wid * 6 + p] = v;
  }
  __syncthreads();
  float z[6], m = -1e30f;
#pragma unroll
  for (int p = 0; p < 6; p++) {
    z[p] = red[p] + red[6 + p] + bp[0];
    m = fmaxf(m, z[p]);
  }
  float es = 0.f;
#pragma unroll
  for (int p = 0; p < 6; p++) {
    z[p] = __expf(z[p] - m);
    es += z[p];
  }
  float inv = 1.f / es;
  float o = 0.f;
#pragma unroll
  for (int p = 0; p < 6; p++) o += z[p] * inv * t[p];
  sk[(size_t)b * 128 + c] = o;
}

// ---------------------------------------------------------------------------
extern "C" void kernel_launch(void* const* d_in, const int* in_sizes, int n_in,
                              void* d_out, int out_size, void* d_ws, size_t ws_size,
                              hipStream_t stream) {
  const float* feature = (const float*)d_in[0];
  const int* nodes_idx[2] = {(const int*)d_in[1], (const int*)d_in[4]};
  const int* edge_src[2] = {(const int*)d_in[2], (const int*)d_in[5]};
  const int* edge_dst[2] = {(const int*)d_in[3], (const int*)d_in[6]};
  const float *Wsk[2], *bsk[2], *bng[2], *bnb[2], *Wg[2], *attS[2], *attD[2],
      *bg[2], *wp[2], *bp[2], *pg[2], *pb[2];
  for (int l = 0; l < 2; l++) {
    int base = 7 + l * 12;
    Wsk[l] = (const float*)d_in[base + 0];
    bsk[l] = (const float*)d_in[base + 1];
    bng[l] = (const float*)d_in[base + 2];
    bnb[l] = (const float*)d_in[base + 3];
    Wg[l] = (const float*)d_in[base + 4];
    attS[l] = (const float*)d_in[base + 5];
    attD[l] = (const float*)d_in[base + 6];
    bg[l] = (const float*)d_in[base + 7];
    wp[l] = (const float*)d_in[base + 8];
    bp[l] = (const float*)d_in[base + 9];
    pg[l] = (const float*)d_in[base + 10];
    pb[l] = (const float*)d_in[base + 11];
  }
  const float* Wm1 = (const float*)d_in[31];
  const float* bm1 = (const float*)d_in[32];
  const float* mg = (const float*)d_in[33];
  const float* mb = (const float*)d_in[34];
  const float* Wm2 = (const float*)d_in[35];
  const float* bm2 = (const float*)d_in[36];

  // ---- workspace layout (float units) ----
  float* ws = (float*)d_ws;
  float* bufG5 = ws;   ws += 102400000;  // alias: fp16 x buffer uses half of it
  float* bufSkip = ws; ws += 12800000;   // 100000 * 128
  float* bufO5 = ws;   ws += 19200000;   // 5 * 30000 * 128
  float* temp = ws;    ws += 19200000;   // pool output (batch*128 used)
  float* f1 = ws;      ws += 1024000;    // 8000 * 128
  float* bufH = ws;    ws += 1024000;    // 8000 * 128
  float* a_s5 = ws;    ws += 800000;     // 5 * 40000 * 4
  float* a_d5 = ws;    ws += 600000;     // 5 * 30000 * 4
  float* logi5 = ws;   ws += 4000000;    // 5 * 200000 * 4
  float* ms5 = ws;     ws += 1200000;    // 5 * 30000 * 8
  float* part = ws;    ws += 5 * NSTATB * 256;
  float* stats = ws;   ws += 7 * 256;    // slot0 skip, 1..5 gat, 6 pool
  int* starts5a = (int*)ws; ws += 150080;     // 5 * 30001 ints (L0)
  int* starts5b = (int*)ws; ws += 50080;      // 5 * 10001 ints (L1)
  short* featB = (short*)ws; ws += 25600000;  // 100000*512 bf16
  short* f0b = (short*)ws;   ws += 1600000;   // 25000*128 bf16
  short* wt_sk0 = (short*)ws; ws += 32768;    // 128*512
  short* wt_g0 = (short*)ws;  ws += 655360;   // 5*512*512
  short* wt_sk1 = (short*)ws; ws += 8192;     // 128*128
  short* wt_g1 = (short*)ws;  ws += 163840;   // 5*512*128
  _Float16* bufG5h = (_Float16*)bufG5;        // 5 * 40000 * 512 fp16 (205 MB)

  auto cdiv = [](int a, int b) { return (a + b - 1) / b; };

  // input-only work first (off the critical path)
  build_starts<<<dim3(cdiv(200001, 256), 5), 256, 0, stream>>>(edge_dst[0],
                                                               200000, 30000, starts5a);
  build_starts<<<dim3(cdiv(80001, 256), 5), 256, 0, stream>>>(edge_dst[1],
                                                              80000, 10000, starts5b);
  conv_bf16<<<2048, 256, 0, stream>>>(feature, featB, 100000L * 512 / 4);
  wT_bf16<<<dim3(16, 4, 1), 256, 0, stream>>>(Wsk[0], wt_sk0, 512, 128, 0);
  wT_bf16<<<dim3(16, 16, 5), 256, 0, stream>>>(Wg[0], wt_g0, 512, 512, 512L * 512);
  wT_bf16<<<dim3(4, 4, 1), 256, 0, stream>>>(Wsk[1], wt_sk1, 128, 128, 0);
  wT_bf16<<<dim3(4, 16, 5), 256, 0, stream>>>(Wg[1], wt_g1, 128, 512, 512L * 128);

  auto run_layer = [&](const short* Xb, int Nf, int din, int li, float* fout,
                       short* foutb, const short* wt_sk, const short* wt_g,
                       int* starts5) {
    const int Nsrc = (li == 0) ? 40000 : 20000;
    const int n_dst = (li == 0) ? 30000 : 10000;
    const int batch = (li == 0) ? 25000 : 8000;
    const int E = (li == 0) ? 200000 : 80000;
    const int mtS = cdiv(Nf, 256);
    const int mtG = cdiv(Nsrc, 256);
    const int GpG = cdiv(mtG, 8) * 8;

    // skip branch GEMM (fp32 out) + stats (slot 0)
    gemm_mfma<<<dim3(mtS, 1, 1), 512, 0, stream>>>(
        Xb, wt_sk, bsk[li], bufSkip, nullptr, nullptr, Nf, din, 128, mtS, 1,
        0, 0, 0, nullptr, nullptr, nullptr, nullptr, 0);
    bn_partial<<<dim3(NSTATB, 1), 128, 0, stream>>>(bufSkip, 0, part, Nf);
    bn_finalize<<<dim3(128, 1), 64, 0, stream>>>(part, NSTATB, Nf, stats);

    // all 5 edge types in one launch per stage (fp16 x out + fused scores)
    gemm_mfma<<<dim3(GpG * 4, 1, 5), 512, 0, stream>>>(
        Xb, wt_g, nullptr, nullptr, bufG5h, nodes_idx[li], Nsrc, din, 512,
        mtG, 4, (long)din * 512, (long)Nsrc * 512, Nsrc,
        attS[li], attD[li], a_s5, a_d5, n_dst);
    edge_logits<<<dim3(cdiv(E, 256), 5), 256, 0, stream>>>(
        edge_src[li], edge_dst[li], a_s5, a_d5, logi5, E, Nsrc * 4, n_dst * 4);
    node_ms<<<dim3(cdiv(n_dst * 4, 256), 5), 256, 0, stream>>>(logi5, starts5,
                                                               ms5, n_dst, E);
    gat_aggregate<<<dim3(n_dst, 5), 64, 0, stream>>>(
        bufG5h, logi5, edge_src[li], starts5, ms5, bg[li], bufO5, n_dst,
        (long)Nsrc * 512, E);
    bn_partial<<<dim3(NSTATB, 5), 128, 0, stream>>>(bufO5, (long)n_dst * 128,
                                                    part, n_dst);
    bn_finalize<<<dim3(128, 5), 64, 0, stream>>>(part, NSTATB, n_dst,
                                                 stats + 256);

    // fused bn+ELU+pool (reads raw bufSkip/bufO5 + stats slots 0..5)
    pool_fused<<<batch, 128, 0, stream>>>(bufSkip, bufO5, (long)n_dst * 128,
                                          stats, bng[li], bnb[li], wp[li],
                                          bp[li], temp, batch);
    bn_partial<<<dim3(NSTATB, 1), 128, 0, stream>>>(temp, 0, part, batch);
    bn_finalize<<<dim3(128, 1), 64, 0, stream>>>(part, NSTATB, batch,
                                                 stats + 6 * 256);
    bn_apply<<<dim3(batch, 1), 128, 0, stream>>>(temp, 0, stats + 6 * 256,
                                                 pg[li], pb[li], 0, fout, foutb,
                                                 0, batch, 128, 0);
  };

  run_layer(featB, 100000, 512, 0, nullptr, f0b, wt_sk0, wt_g0, starts5a);
  run_layer(f0b, 25000, 128, 1, f1, nullptr, wt_sk1, wt_g1, starts5b);

  gemm_bias<<<dim3(cdiv(8000, 64), 2), 256, 0, stream>>>(f1, Wm1, bm1, bufSkip,
                                                         nullptr, 8000, 128, 128);
  bn_partial<<<dim3(NSTATB, 1), 128, 0, stream>>>(bufSkip, 0, part, 8000);
  bn_finalize<<<dim3(128, 1), 64, 0, stream>>>(part, NSTATB, 8000, stats);
  bn_apply<<<dim3(8000, 1), 128, 0, stream>>>(bufSkip, 0, stats, mg, mb, 0,
                                              bufH, nullptr, 0, 8000, 128, 2);
  gemm_bias<<<dim3(cdiv(8000, 64), 3), 256, 0, stream>>>(
      bufH, Wm2, bm2, (float*)d_out, nullptr, 8000, 128, 153);
}